// Round 1
// baseline (1324.175 us; speedup 1.0000x reference)
//
#include <hip/hip_runtime.h>

#define D_NODE 128
#define D_EDGE 64
#define D_IN   192
#define NEG    0.01f
#define LN_EPS 1e-5f

// ---------------------------------------------------------------------------
// Kernel 1: per-edge  h = concat(x[row], edge_attr)  ->  y = h @ W1 + b1
//           -> LayerNorm -> LeakyReLU -> atomic scatter-add into sums[col],
//           counts[col] += 1.
// Block = 256 threads, 16 edges per block.
// Thread (j = tid&127, g = tid>>7) computes column j for 8 edges (g*8..g*8+7).
// ---------------------------------------------------------------------------
__global__ __launch_bounds__(256) void edge_mlp_scatter(
    const float* __restrict__ x,
    const int*   __restrict__ edge_index,   // [2*E] (row-major: row[E], col[E])
    const float* __restrict__ edge_attr,    // [E, 64]
    const float* __restrict__ W1,           // [192, 128]
    const float* __restrict__ b1,
    const float* __restrict__ g1,
    const float* __restrict__ be1,
    float* __restrict__ sums,               // [N, 128]
    float* __restrict__ counts,             // [N]
    int E)
{
    __shared__ float h[16][D_IN];           // 12 KB
    __shared__ int   scol[16];
    __shared__ float rS[4][8], rS2[4][8];

    const int tid = threadIdx.x;
    const int e0  = blockIdx.x * 16;

    // gather + concat into LDS
    for (int idx = tid; idx < 16 * D_IN; idx += 256) {
        int e = idx / D_IN;
        int k = idx - e * D_IN;
        int ge = e0 + e;
        float v = 0.f;
        if (ge < E) {
            if (k < D_NODE) v = x[(size_t)edge_index[ge] * D_NODE + k];
            else            v = edge_attr[(size_t)ge * D_EDGE + (k - D_NODE)];
        }
        h[e][k] = v;
    }
    if (tid < 16) {
        int ge = e0 + tid;
        scol[tid] = (ge < E) ? edge_index[E + ge] : 0;
    }
    __syncthreads();

    const int j    = tid & 127;
    const int g    = tid >> 7;   // which half (edge group)
    const int w    = tid >> 6;   // wave id 0..3
    const int lane = tid & 63;

    const float bj = b1[j];
    float acc[8];
    #pragma unroll
    for (int i = 0; i < 8; ++i) acc[i] = bj;

    const float* hrow = &h[g * 8][0];
    #pragma unroll 2
    for (int k = 0; k < D_IN; ++k) {
        float wv = W1[k * D_NODE + j];      // reused by 8 edges; both halves hit same line
        #pragma unroll
        for (int i = 0; i < 8; ++i)
            acc[i] = fmaf(hrow[i * D_IN + k], wv, acc[i]);
    }

    // per-edge mean / mean-of-squares over the 128 columns.
    // Columns of edge (g*8+i) live in waves 2g and 2g+1.
    #pragma unroll
    for (int i = 0; i < 8; ++i) {
        float s  = acc[i];
        float s2 = acc[i] * acc[i];
        #pragma unroll
        for (int off = 32; off > 0; off >>= 1) {
            s  += __shfl_down(s,  off);
            s2 += __shfl_down(s2, off);
        }
        if (lane == 0) { rS[w][i] = s; rS2[w][i] = s2; }
    }
    __syncthreads();

    const float gj  = g1[j];
    const float bej = be1[j];
    #pragma unroll
    for (int i = 0; i < 8; ++i) {
        int e  = g * 8 + i;
        int ge = e0 + e;
        if (ge >= E) continue;
        float S    = rS[2 * g][i]  + rS[2 * g + 1][i];
        float S2   = rS2[2 * g][i] + rS2[2 * g + 1][i];
        float mu   = S * (1.f / 128.f);
        float var  = S2 * (1.f / 128.f) - mu * mu;
        float rstd = rsqrtf(var + LN_EPS);
        float y = (acc[i] - mu) * rstd * gj + bej;
        y = (y > 0.f) ? y : NEG * y;                    // LeakyReLU
        int c = scol[e];
        atomicAdd(&sums[(size_t)c * D_NODE + j], y);
        if (j == 0) atomicAdd(&counts[c], 1.0f);
    }
}

// ---------------------------------------------------------------------------
// Kernel 2: per-node  m = sums[n]/max(counts[n],1)  ->  y = m @ W2 + b2
//           -> LayerNorm -> LeakyReLU -> (+x) -> LeakyReLU -> out
// Block = 256 threads, 16 nodes per block.
// ---------------------------------------------------------------------------
__global__ __launch_bounds__(256) void node_mlp(
    const float* __restrict__ sums,
    const float* __restrict__ counts,
    const float* __restrict__ x,
    const float* __restrict__ W2,           // [128, 128]
    const float* __restrict__ b2,
    const float* __restrict__ g2,
    const float* __restrict__ be2,
    float* __restrict__ out,
    int N)
{
    __shared__ float h[16][D_NODE];         // 8 KB
    __shared__ float rS[4][8], rS2[4][8];

    const int tid = threadIdx.x;
    const int n0  = blockIdx.x * 16;

    for (int idx = tid; idx < 16 * D_NODE; idx += 256) {
        int e = idx >> 7;
        int k = idx & 127;
        int gn = n0 + e;
        float v = 0.f;
        if (gn < N) {
            float c = counts[gn];
            v = sums[(size_t)gn * D_NODE + k] / fmaxf(c, 1.f);
        }
        h[e][k] = v;
    }
    __syncthreads();

    const int j    = tid & 127;
    const int g    = tid >> 7;
    const int w    = tid >> 6;
    const int lane = tid & 63;

    const float bj = b2[j];
    float acc[8];
    #pragma unroll
    for (int i = 0; i < 8; ++i) acc[i] = bj;

    const float* hrow = &h[g * 8][0];
    #pragma unroll 2
    for (int k = 0; k < D_NODE; ++k) {
        float wv = W2[k * D_NODE + j];
        #pragma unroll
        for (int i = 0; i < 8; ++i)
            acc[i] = fmaf(hrow[i * D_NODE + k], wv, acc[i]);
    }

    #pragma unroll
    for (int i = 0; i < 8; ++i) {
        float s  = acc[i];
        float s2 = acc[i] * acc[i];
        #pragma unroll
        for (int off = 32; off > 0; off >>= 1) {
            s  += __shfl_down(s,  off);
            s2 += __shfl_down(s2, off);
        }
        if (lane == 0) { rS[w][i] = s; rS2[w][i] = s2; }
    }
    __syncthreads();

    const float gj  = g2[j];
    const float bej = be2[j];
    #pragma unroll
    for (int i = 0; i < 8; ++i) {
        int e  = g * 8 + i;
        int gn = n0 + e;
        if (gn >= N) continue;
        float S    = rS[2 * g][i]  + rS[2 * g + 1][i];
        float S2   = rS2[2 * g][i] + rS2[2 * g + 1][i];
        float mu   = S * (1.f / 128.f);
        float var  = S2 * (1.f / 128.f) - mu * mu;
        float rstd = rsqrtf(var + LN_EPS);
        float y = (acc[i] - mu) * rstd * gj + bej;
        y = (y > 0.f) ? y : NEG * y;                    // LeakyReLU
        float r = y + x[(size_t)gn * D_NODE + j];       // residual
        r = (r > 0.f) ? r : NEG * r;                    // LeakyReLU
        out[(size_t)gn * D_NODE + j] = r;
    }
}

// ---------------------------------------------------------------------------
extern "C" void kernel_launch(void* const* d_in, const int* in_sizes, int n_in,
                              void* d_out, int out_size, void* d_ws, size_t ws_size,
                              hipStream_t stream) {
    const float* x          = (const float*)d_in[0];
    const int*   edge_index = (const int*)  d_in[1];
    const float* edge_attr  = (const float*)d_in[2];
    const float* W1         = (const float*)d_in[3];
    const float* b1         = (const float*)d_in[4];
    const float* g1         = (const float*)d_in[5];
    const float* be1        = (const float*)d_in[6];
    const float* W2         = (const float*)d_in[7];
    const float* b2         = (const float*)d_in[8];
    const float* g2         = (const float*)d_in[9];
    const float* be2        = (const float*)d_in[10];

    const int N = in_sizes[0] / D_NODE;     // 50000
    const int E = in_sizes[1] / 2;          // 600000

    float* sums   = (float*)d_ws;                      // [N,128]
    float* counts = sums + (size_t)N * D_NODE;         // [N]

    hipMemsetAsync(d_ws, 0, ((size_t)N * D_NODE + (size_t)N) * sizeof(float), stream);

    dim3 blk(256);
    edge_mlp_scatter<<<dim3((E + 15) / 16), blk, 0, stream>>>(
        x, edge_index, edge_attr, W1, b1, g1, be1, sums, counts, E);
    node_mlp<<<dim3((N + 15) / 16), blk, 0, stream>>>(
        sums, counts, x, W2, b2, g2, be2, (float*)d_out, N);
}

// Round 2
// 592.998 us; speedup vs baseline: 2.2330x; 2.2330x over previous
//
#include <hip/hip_runtime.h>

#define D_NODE 128
#define D_EDGE 64
#define D_IN   192
#define NEG    0.01f
#define LN_EPS 1e-5f

typedef short bf16x8 __attribute__((ext_vector_type(8)));
typedef float f32x4  __attribute__((ext_vector_type(4)));

__device__ __forceinline__ unsigned f2bf(float f) {
    unsigned u = __builtin_bit_cast(unsigned, f);
    return (u + 0x7FFFu + ((u >> 16) & 1u)) >> 16;   // RNE
}
__device__ __forceinline__ unsigned pk2(float a, float b) {
    return f2bf(a) | (f2bf(b) << 16);
}

// ---------------------------------------------------------------------------
// Edge kernel: per 64-edge tile
//   h = concat(x[row], edge_attr) (bf16, LDS)  ->  y = h @ W1 + b1 (MFMA)
//   -> LayerNorm -> LeakyReLU -> fp32 atomic scatter into sums/counts.
// 256 threads = 4 waves. Wave w owns output cols [w*32, w*32+32).
// W1 fragments live in registers (loaded once per persistent block).
// mfma_f32_16x16x32_bf16: A[m=lane&15][k=(lane>>4)*8+j], B^T[n=lane&15][k=...],
// C/D: col=lane&15, row=(lane>>4)*4+reg  (HW-verified layouts).
// ---------------------------------------------------------------------------
__global__ __launch_bounds__(256) void edge_mfma_scatter(
    const float* __restrict__ x,
    const int*   __restrict__ edge_index,   // [2*E]
    const float* __restrict__ edge_attr,    // [E, 64]
    const float* __restrict__ W1,           // [192, 128] (k-major)
    const float* __restrict__ b1,
    const float* __restrict__ g1,
    const float* __restrict__ be1,
    float* __restrict__ sums,               // [N, 128]
    float* __restrict__ counts,             // [N]
    int E, int ntiles)
{
    __shared__ unsigned short h[64][200];   // 25600 B; pad 200 -> 2-way (free) banks
    __shared__ float rS [64][4];            // per-edge per-wave partial sum
    __shared__ float rS2[64][4];            // per-edge per-wave partial sum-of-squares
    __shared__ int   scol[64];

    const int tid = threadIdx.x;
    const int w   = tid >> 6;       // wave 0..3
    const int l   = tid & 63;
    const int lm  = l & 15;         // fragment row/col index
    const int q   = l >> 4;         // quad 0..3
    const int q8  = q * 8;

    // ---- W1 fragments for this wave's 32 cols: registers, once per block ----
    bf16x8 Bfr[2][6];
    float  b1v[2], g1v[2], bev[2];
    #pragma unroll
    for (int c2 = 0; c2 < 2; ++c2) {
        const int n = (2 * w + c2) * 16 + lm;
        b1v[c2] = b1[n]; g1v[c2] = g1[n]; bev[c2] = be1[n];
        #pragma unroll
        for (int kt = 0; kt < 6; ++kt) {
            bf16x8 f;
            #pragma unroll
            for (int j = 0; j < 8; ++j) {
                const int k = kt * 32 + q8 + j;
                f[j] = (short)f2bf(W1[k * 128 + n]);
            }
            Bfr[c2][kt] = f;
        }
    }

    for (int tile = blockIdx.x; tile < ntiles; tile += gridDim.x) {
        const int e0 = tile * 64;

        // ---- stage h tile (gather + concat + fp32->bf16) ----
        {
            const int e  = tid >> 2;       // edge within tile
            const int qq = tid & 3;        // quarter of the row
            const int ge = e0 + e;
            if (ge < E) {
                const int row = edge_index[ge];
                const float4* xr = (const float4*)(x + (size_t)row * D_NODE);
                #pragma unroll
                for (int i = 0; i < 8; ++i) {           // 32 cols of x part
                    float4 v = xr[qq * 8 + i];
                    *(uint2*)&h[e][qq * 32 + i * 4] =
                        make_uint2(pk2(v.x, v.y), pk2(v.z, v.w));
                }
                const float4* ar = (const float4*)(edge_attr + (size_t)ge * D_EDGE);
                #pragma unroll
                for (int i = 0; i < 4; ++i) {           // 16 cols of attr part
                    float4 v = ar[qq * 4 + i];
                    *(uint2*)&h[e][128 + qq * 16 + i * 4] =
                        make_uint2(pk2(v.x, v.y), pk2(v.z, v.w));
                }
            } else {
                #pragma unroll
                for (int i = 0; i < 8; ++i)
                    *(uint2*)&h[e][qq * 32 + i * 4] = make_uint2(0u, 0u);
                #pragma unroll
                for (int i = 0; i < 4; ++i)
                    *(uint2*)&h[e][128 + qq * 16 + i * 4] = make_uint2(0u, 0u);
            }
            if (tid < 64)
                scol[tid] = (e0 + tid < E) ? edge_index[E + e0 + tid] : -1;
        }
        __syncthreads();

        // ---- MFMA: 4 edge-tiles x 2 col-tiles, K=192 ----
        f32x4 acc[4][2];
        #pragma unroll
        for (int et = 0; et < 4; ++et)
            #pragma unroll
            for (int c2 = 0; c2 < 2; ++c2)
                acc[et][c2] = (f32x4){0.f, 0.f, 0.f, 0.f};

        #pragma unroll
        for (int et = 0; et < 4; ++et) {
            bf16x8 Afr[6];
            #pragma unroll
            for (int kt = 0; kt < 6; ++kt)
                Afr[kt] = *(const bf16x8*)&h[et * 16 + lm][kt * 32 + q8];
            #pragma unroll
            for (int c2 = 0; c2 < 2; ++c2)
                #pragma unroll
                for (int kt = 0; kt < 6; ++kt)
                    acc[et][c2] = __builtin_amdgcn_mfma_f32_16x16x32_bf16(
                        Afr[kt], Bfr[c2][kt], acc[et][c2], 0, 0, 0);
        }

        // ---- bias + partial LN sums over this wave's 32 cols ----
        #pragma unroll
        for (int et = 0; et < 4; ++et) {
            #pragma unroll
            for (int r = 0; r < 4; ++r) {
                float v0 = acc[et][0][r] + b1v[0];
                float v1 = acc[et][1][r] + b1v[1];
                acc[et][0][r] = v0;
                acc[et][1][r] = v1;
                float s  = v0 + v1;
                float s2 = v0 * v0 + v1 * v1;
                #pragma unroll
                for (int off = 1; off < 16; off <<= 1) {
                    s  += __shfl_xor(s,  off, 16);
                    s2 += __shfl_xor(s2, off, 16);
                }
                if (lm == 0) {
                    const int em = et * 16 + q * 4 + r;
                    rS [em][w] = s;
                    rS2[em][w] = s2;
                }
            }
        }
        __syncthreads();

        // ---- finalize LN, LeakyReLU, atomic scatter ----
        #pragma unroll
        for (int et = 0; et < 4; ++et) {
            #pragma unroll
            for (int r = 0; r < 4; ++r) {
                const int em = et * 16 + q * 4 + r;
                float4 p  = *(const float4*)&rS [em][0];
                float4 p2 = *(const float4*)&rS2[em][0];
                const float S    = (p.x  + p.y)  + (p.z  + p.w);
                const float S2   = (p2.x + p2.y) + (p2.z + p2.w);
                const float mu   = S * (1.f / 128.f);
                const float var  = S2 * (1.f / 128.f) - mu * mu;
                const float rstd = rsqrtf(var + LN_EPS);
                const int   c    = scol[em];
                if (c >= 0) {
                    #pragma unroll
                    for (int c2 = 0; c2 < 2; ++c2) {
                        float y = (acc[et][c2][r] - mu) * rstd * g1v[c2] + bev[c2];
                        y = (y > 0.f) ? y : NEG * y;
                        atomicAdd(&sums[(size_t)c * D_NODE + (2 * w + c2) * 16 + lm], y);
                    }
                    if (w == 0 && lm == 0) atomicAdd(&counts[c], 1.0f);
                }
            }
        }
        __syncthreads();   // protect h/rS/scol before next iteration's staging
    }
}

// ---------------------------------------------------------------------------
// Kernel 2: per-node  m = sums[n]/max(counts[n],1)  ->  y = m @ W2 + b2
//           -> LayerNorm -> LeakyReLU -> (+x) -> LeakyReLU -> out
// (unchanged from round 0; ~10% of runtime — next lever after scatter)
// ---------------------------------------------------------------------------
__global__ __launch_bounds__(256) void node_mlp(
    const float* __restrict__ sums,
    const float* __restrict__ counts,
    const float* __restrict__ x,
    const float* __restrict__ W2,
    const float* __restrict__ b2,
    const float* __restrict__ g2,
    const float* __restrict__ be2,
    float* __restrict__ out,
    int N)
{
    __shared__ float h[16][D_NODE];
    __shared__ float rS[4][8], rS2[4][8];

    const int tid = threadIdx.x;
    const int n0  = blockIdx.x * 16;

    for (int idx = tid; idx < 16 * D_NODE; idx += 256) {
        int e = idx >> 7;
        int k = idx & 127;
        int gn = n0 + e;
        float v = 0.f;
        if (gn < N) {
            float c = counts[gn];
            v = sums[(size_t)gn * D_NODE + k] / fmaxf(c, 1.f);
        }
        h[e][k] = v;
    }
    __syncthreads();

    const int j    = tid & 127;
    const int g    = tid >> 7;
    const int w    = tid >> 6;
    const int lane = tid & 63;

    const float bj = b2[j];
    float acc[8];
    #pragma unroll
    for (int i = 0; i < 8; ++i) acc[i] = bj;

    const float* hrow = &h[g * 8][0];
    #pragma unroll 2
    for (int k = 0; k < D_NODE; ++k) {
        float wv = W2[k * D_NODE + j];
        #pragma unroll
        for (int i = 0; i < 8; ++i)
            acc[i] = fmaf(hrow[i * D_NODE + k], wv, acc[i]);
    }

    #pragma unroll
    for (int i = 0; i < 8; ++i) {
        float s  = acc[i];
        float s2 = acc[i] * acc[i];
        #pragma unroll
        for (int off = 32; off > 0; off >>= 1) {
            s  += __shfl_down(s,  off);
            s2 += __shfl_down(s2, off);
        }
        if (lane == 0) { rS[w][i] = s; rS2[w][i] = s2; }
    }
    __syncthreads();

    const float gj  = g2[j];
    const float bej = be2[j];
    #pragma unroll
    for (int i = 0; i < 8; ++i) {
        int e  = g * 8 + i;
        int gn = n0 + e;
        if (gn >= N) continue;
        float S    = rS[2 * g][i]  + rS[2 * g + 1][i];
        float S2   = rS2[2 * g][i] + rS2[2 * g + 1][i];
        float mu   = S * (1.f / 128.f);
        float var  = S2 * (1.f / 128.f) - mu * mu;
        float rstd = rsqrtf(var + LN_EPS);
        float y = (acc[i] - mu) * rstd * gj + bej;
        y = (y > 0.f) ? y : NEG * y;
        float r = y + x[(size_t)gn * D_NODE + j];
        r = (r > 0.f) ? r : NEG * r;
        out[(size_t)gn * D_NODE + j] = r;
    }
}

// ---------------------------------------------------------------------------
extern "C" void kernel_launch(void* const* d_in, const int* in_sizes, int n_in,
                              void* d_out, int out_size, void* d_ws, size_t ws_size,
                              hipStream_t stream) {
    const float* x          = (const float*)d_in[0];
    const int*   edge_index = (const int*)  d_in[1];
    const float* edge_attr  = (const float*)d_in[2];
    const float* W1         = (const float*)d_in[3];
    const float* b1         = (const float*)d_in[4];
    const float* g1         = (const float*)d_in[5];
    const float* be1        = (const float*)d_in[6];
    const float* W2         = (const float*)d_in[7];
    const float* b2         = (const float*)d_in[8];
    const float* g2         = (const float*)d_in[9];
    const float* be2        = (const float*)d_in[10];

    const int N = in_sizes[0] / D_NODE;     // 50000
    const int E = in_sizes[1] / 2;          // 600000

    float* sums   = (float*)d_ws;                      // [N,128]
    float* counts = sums + (size_t)N * D_NODE;         // [N]

    hipMemsetAsync(d_ws, 0, ((size_t)N * D_NODE + (size_t)N) * sizeof(float), stream);

    const int ntiles = (E + 63) / 64;
    const int grid   = ntiles < 1024 ? ntiles : 1024;

    edge_mfma_scatter<<<dim3(grid), dim3(256), 0, stream>>>(
        x, edge_index, edge_attr, W1, b1, g1, be1, sums, counts, E, ntiles);
    node_mlp<<<dim3((N + 15) / 16), dim3(256), 0, stream>>>(
        sums, counts, x, W2, b2, g2, be2, (float*)d_out, N);
}

// Round 3
// 509.656 us; speedup vs baseline: 2.5982x; 1.1635x over previous
//
#include <hip/hip_runtime.h>

#define D_NODE 128
#define D_EDGE 64
#define D_IN   192
#define NEG    0.01f
#define LN_EPS 1e-5f

typedef short bf16x8 __attribute__((ext_vector_type(8)));
typedef float f32x4  __attribute__((ext_vector_type(4)));

__device__ __forceinline__ unsigned f2bf(float f) {
    unsigned u = __builtin_bit_cast(unsigned, f);
    return (u + 0x7FFFu + ((u >> 16) & 1u)) >> 16;   // RNE
}
__device__ __forceinline__ unsigned pk2(float a, float b) {
    return f2bf(a) | (f2bf(b) << 16);
}
__device__ __forceinline__ float bf2f(unsigned short s) {
    unsigned u = ((unsigned)s) << 16;
    return __builtin_bit_cast(float, u);
}

// ---------------------------------------------------------------------------
// Counting sort of edges by destination: hist -> exclusive scan -> bucket.
// ---------------------------------------------------------------------------
__global__ void k_hist(const int* __restrict__ ei, int* __restrict__ hist, int E) {
    int i = blockIdx.x * blockDim.x + threadIdx.x;
    int stride = gridDim.x * blockDim.x;
    for (int e = i; e < E; e += stride) atomicAdd(&hist[ei[E + e]], 1);
}

__global__ __launch_bounds__(1024) void k_scanA(const int* __restrict__ hist,
                                                int* __restrict__ base,
                                                int* __restrict__ blockTot, int N) {
    __shared__ int wsum[16], woff[16];
    const int t = threadIdx.x, b = blockIdx.x;
    const int i = b * 1024 + t;
    const int lane = t & 63, w = t >> 6;
    int v = (i < N) ? hist[i] : 0;
    int x = v;
    #pragma unroll
    for (int d = 1; d < 64; d <<= 1) { int u = __shfl_up(x, d); if (lane >= d) x += u; }
    if (lane == 63) wsum[w] = x;
    __syncthreads();
    if (t < 16) {
        int y = wsum[t];
        #pragma unroll
        for (int d = 1; d < 16; d <<= 1) { int u = __shfl_up(y, d, 16); if (t >= d) y += u; }
        woff[t] = y - wsum[t];
    }
    __syncthreads();
    int incl = x + woff[w];
    if (i < N) base[i] = incl - v;            // exclusive within block
    if (t == 1023) blockTot[b] = incl;
}

__global__ void k_scanB(int* __restrict__ blockTot, int NB) {   // 1 block, 64 thr, NB<=64
    int t = threadIdx.x;
    int v = (t < NB) ? blockTot[t] : 0;
    int x = v;
    #pragma unroll
    for (int d = 1; d < 64; d <<= 1) { int u = __shfl_up(x, d); if (t >= d) x += u; }
    if (t < NB) blockTot[t] = x - v;          // exclusive block offsets
}

__global__ __launch_bounds__(1024) void k_scanC(int* __restrict__ base,
                                                const int* __restrict__ blockTot, int N) {
    int i = blockIdx.x * 1024 + threadIdx.x;
    if (i < N) base[i] += blockTot[blockIdx.x];
}

__global__ void k_bucket(const int* __restrict__ ei, int* __restrict__ base,
                         int* __restrict__ perm, int* __restrict__ srcrow,
                         int* __restrict__ dstcol, int E) {
    int i = blockIdx.x * blockDim.x + threadIdx.x;
    int stride = gridDim.x * blockDim.x;
    for (int e = i; e < E; e += stride) {
        int c = ei[E + e];
        int r = ei[e];
        int p = atomicAdd(&base[c], 1);       // consumes base (cursor)
        perm[p]   = e;
        srcrow[p] = r;
        dstcol[p] = c;
    }
}

// ---------------------------------------------------------------------------
// Edge kernel over DEST-SORTED edges, 64-edge tiles:
//   gather+concat (bf16 LDS) -> MFMA y = h@W1+b1 -> LN -> LeakyReLU
//   -> y round-trip through LDS (bf16, aliased onto h)
//   -> segmented sum over dest runs: interior runs = plain store,
//      boundary-touching runs = atomicAdd.  (atomics: 76.8M -> ~5M)
// 256 threads = 4 waves; wave w owns cols [32w,32w+32); W1 frags in registers.
// ---------------------------------------------------------------------------
__global__ __launch_bounds__(256) void edge_mfma_seg(
    const float* __restrict__ x,
    const float* __restrict__ edge_attr,
    const int*   __restrict__ perm,
    const int*   __restrict__ srcrow,
    const int*   __restrict__ dstcol,
    const float* __restrict__ W1,
    const float* __restrict__ b1,
    const float* __restrict__ g1,
    const float* __restrict__ be1,
    float* __restrict__ sums,
    int E, int ntiles)
{
    __shared__ unsigned short h[64][200];     // 25.6 KB; also holds y (bf16) later
    __shared__ float rS [64][4], rS2[64][4];
    __shared__ int   scol[64];
    __shared__ unsigned long long maskSh;

    const int tid = threadIdx.x;
    const int w   = tid >> 6;
    const int l   = tid & 63;
    const int lm  = l & 15;
    const int q   = l >> 4;
    const int q8  = q * 8;

    // W1 fragments, bias/gamma/beta for this wave's 32 cols (once per block)
    bf16x8 Bfr[2][6];
    float  b1v[2], g1v[2], bev[2];
    #pragma unroll
    for (int c2 = 0; c2 < 2; ++c2) {
        const int n = (2 * w + c2) * 16 + lm;
        b1v[c2] = b1[n]; g1v[c2] = g1[n]; bev[c2] = be1[n];
        #pragma unroll
        for (int kt = 0; kt < 6; ++kt) {
            bf16x8 f;
            #pragma unroll
            for (int j = 0; j < 8; ++j)
                f[j] = (short)f2bf(W1[(kt * 32 + q8 + j) * 128 + n]);
            Bfr[c2][kt] = f;
        }
    }

    for (int tile = blockIdx.x; tile < ntiles; tile += gridDim.x) {
        const int e0 = tile * 64;

        // ---- stage h tile ----
        {
            const int e  = tid >> 2;
            const int qq = tid & 3;
            const int ge = e0 + e;
            if (ge < E) {
                const int row = srcrow[ge];
                const int eid = perm[ge];
                const float4* xr = (const float4*)(x + (size_t)row * D_NODE);
                #pragma unroll
                for (int i = 0; i < 8; ++i) {
                    float4 v = xr[qq * 8 + i];
                    *(uint2*)&h[e][qq * 32 + i * 4] =
                        make_uint2(pk2(v.x, v.y), pk2(v.z, v.w));
                }
                const float4* ar = (const float4*)(edge_attr + (size_t)eid * D_EDGE);
                #pragma unroll
                for (int i = 0; i < 4; ++i) {
                    float4 v = ar[qq * 4 + i];
                    *(uint2*)&h[e][128 + qq * 16 + i * 4] =
                        make_uint2(pk2(v.x, v.y), pk2(v.z, v.w));
                }
            } else {
                #pragma unroll
                for (int i = 0; i < 8; ++i)
                    *(uint2*)&h[e][qq * 32 + i * 4] = make_uint2(0u, 0u);
                #pragma unroll
                for (int i = 0; i < 4; ++i)
                    *(uint2*)&h[e][128 + qq * 16 + i * 4] = make_uint2(0u, 0u);
            }
            if (tid < 64)
                scol[tid] = (e0 + tid < E) ? dstcol[e0 + tid] : -1;
        }
        __syncthreads();                       // B1: h/scol ready

        // ---- MFMA: 4 edge-tiles x 2 col-tiles, K=192 ----
        f32x4 acc[4][2];
        #pragma unroll
        for (int et = 0; et < 4; ++et)
            #pragma unroll
            for (int c2 = 0; c2 < 2; ++c2)
                acc[et][c2] = (f32x4){0.f, 0.f, 0.f, 0.f};

        #pragma unroll
        for (int et = 0; et < 4; ++et) {
            bf16x8 Afr[6];
            #pragma unroll
            for (int kt = 0; kt < 6; ++kt)
                Afr[kt] = *(const bf16x8*)&h[et * 16 + lm][kt * 32 + q8];
            #pragma unroll
            for (int c2 = 0; c2 < 2; ++c2)
                #pragma unroll
                for (int kt = 0; kt < 6; ++kt)
                    acc[et][c2] = __builtin_amdgcn_mfma_f32_16x16x32_bf16(
                        Afr[kt], Bfr[c2][kt], acc[et][c2], 0, 0, 0);
        }

        // ---- bias + LN partial sums ----
        #pragma unroll
        for (int et = 0; et < 4; ++et) {
            #pragma unroll
            for (int r = 0; r < 4; ++r) {
                float v0 = acc[et][0][r] + b1v[0];
                float v1 = acc[et][1][r] + b1v[1];
                acc[et][0][r] = v0;
                acc[et][1][r] = v1;
                float s  = v0 + v1;
                float s2 = v0 * v0 + v1 * v1;
                #pragma unroll
                for (int off = 1; off < 16; off <<= 1) {
                    s  += __shfl_xor(s,  off, 16);
                    s2 += __shfl_xor(s2, off, 16);
                }
                if (lm == 0) {
                    const int em = et * 16 + q * 4 + r;
                    rS [em][w] = s;
                    rS2[em][w] = s2;
                }
            }
        }
        __syncthreads();                       // B2: rS ready; all h reads done

        // ---- run-start mask (wave 0) ----
        if (tid < 64) {
            int me = scol[tid];
            int pv = (tid == 0) ? (me ^ 1) : scol[tid - 1];   // force start at 0
            unsigned long long m = __ballot(me != pv);
            if (tid == 0) maskSh = m;
        }

        // ---- finalize LN + LeakyReLU, write y (bf16) back into h ----
        #pragma unroll
        for (int et = 0; et < 4; ++et) {
            #pragma unroll
            for (int r = 0; r < 4; ++r) {
                const int em = et * 16 + q * 4 + r;
                float4 p  = *(const float4*)&rS [em][0];
                float4 p2 = *(const float4*)&rS2[em][0];
                const float S    = (p.x  + p.y)  + (p.z  + p.w);
                const float S2   = (p2.x + p2.y) + (p2.z + p2.w);
                const float mu   = S * (1.f / 128.f);
                const float var  = S2 * (1.f / 128.f) - mu * mu;
                const float rstd = rsqrtf(var + LN_EPS);
                #pragma unroll
                for (int c2 = 0; c2 < 2; ++c2) {
                    float y = (acc[et][c2][r] - mu) * rstd * g1v[c2] + bev[c2];
                    y = (y > 0.f) ? y : NEG * y;
                    h[em][(2 * w + c2) * 16 + lm] = (unsigned short)f2bf(y);
                }
            }
        }
        __syncthreads();                       // B3: y + mask ready

        // ---- segmented reduce over dest runs ----
        {
            const unsigned long long mask = maskSh;
            const int g  = tid >> 7;           // 0/1: em-range half
            const int j  = tid & 127;
            const int lo = g * 32, hi = lo + 32;
            float s = 0.f;
            int rs = lo;
            for (int em = lo; em < hi; ++em) {
                s += bf2f(h[em][j]);
                const int nx = em + 1;
                const bool isEnd = (nx == hi) || ((mask >> nx) & 1ull);
                if (isEnd) {
                    const int dest = scol[em];
                    if (dest >= 0) {
                        // run fully inside this tile+half <=> genuine start & end
                        const bool sg = (rs > 0) && ((mask >> rs) & 1ull);
                        const bool eg = (em < 63) && ((mask >> nx) & 1ull);
                        float* p = &sums[(size_t)dest * D_NODE + j];
                        if (sg && eg) *p = s;
                        else          atomicAdd(p, s);
                    }
                    s = 0.f; rs = nx;
                }
            }
        }
        __syncthreads();                       // B4: protect h/scol for next tile
    }
}

// ---------------------------------------------------------------------------
// Node kernel (MFMA): m = sums/cnt -> y = m@W2+b2 -> LN -> LeakyReLU
//                     -> +x -> LeakyReLU -> out.  64-node tiles.
// ---------------------------------------------------------------------------
__global__ __launch_bounds__(256) void node_mfma(
    const float* __restrict__ sums,
    const int*   __restrict__ hist,
    const float* __restrict__ x,
    const float* __restrict__ W2,
    const float* __restrict__ b2,
    const float* __restrict__ g2,
    const float* __restrict__ be2,
    float* __restrict__ out,
    int N)
{
    __shared__ unsigned short h[64][136];     // 17.4 KB
    __shared__ float rS [64][4], rS2[64][4];

    const int tid = threadIdx.x;
    const int w   = tid >> 6;
    const int l   = tid & 63;
    const int lm  = l & 15;
    const int q   = l >> 4;
    const int q8  = q * 8;

    bf16x8 Bfr[2][4];
    float  b2v[2], g2v[2], bev[2];
    #pragma unroll
    for (int c2 = 0; c2 < 2; ++c2) {
        const int n = (2 * w + c2) * 16 + lm;
        b2v[c2] = b2[n]; g2v[c2] = g2[n]; bev[c2] = be2[n];
        #pragma unroll
        for (int kt = 0; kt < 4; ++kt) {
            bf16x8 f;
            #pragma unroll
            for (int j = 0; j < 8; ++j)
                f[j] = (short)f2bf(W2[(kt * 32 + q8 + j) * 128 + n]);
            Bfr[c2][kt] = f;
        }
    }

    const int n0 = blockIdx.x * 64;

    // stage m = sums/cnt (bf16)
    {
        const int e  = tid >> 2;
        const int qq = tid & 3;
        const int gn = n0 + e;
        if (gn < N) {
            const int cnt = hist[gn];
            const float sc = (cnt > 0) ? 1.f / (float)cnt : 0.f;
            const float4* sr = (const float4*)(sums + (size_t)gn * D_NODE);
            #pragma unroll
            for (int i = 0; i < 8; ++i) {
                float4 v = sr[qq * 8 + i];
                *(uint2*)&h[e][qq * 32 + i * 4] =
                    make_uint2(pk2(v.x * sc, v.y * sc), pk2(v.z * sc, v.w * sc));
            }
        } else {
            #pragma unroll
            for (int i = 0; i < 8; ++i)
                *(uint2*)&h[e][qq * 32 + i * 4] = make_uint2(0u, 0u);
        }
    }
    __syncthreads();

    f32x4 acc[4][2];
    #pragma unroll
    for (int et = 0; et < 4; ++et)
        #pragma unroll
        for (int c2 = 0; c2 < 2; ++c2)
            acc[et][c2] = (f32x4){0.f, 0.f, 0.f, 0.f};

    #pragma unroll
    for (int et = 0; et < 4; ++et) {
        bf16x8 Afr[4];
        #pragma unroll
        for (int kt = 0; kt < 4; ++kt)
            Afr[kt] = *(const bf16x8*)&h[et * 16 + lm][kt * 32 + q8];
        #pragma unroll
        for (int c2 = 0; c2 < 2; ++c2)
            #pragma unroll
            for (int kt = 0; kt < 4; ++kt)
                acc[et][c2] = __builtin_amdgcn_mfma_f32_16x16x32_bf16(
                    Afr[kt], Bfr[c2][kt], acc[et][c2], 0, 0, 0);
    }

    #pragma unroll
    for (int et = 0; et < 4; ++et) {
        #pragma unroll
        for (int r = 0; r < 4; ++r) {
            float v0 = acc[et][0][r] + b2v[0];
            float v1 = acc[et][1][r] + b2v[1];
            acc[et][0][r] = v0;
            acc[et][1][r] = v1;
            float s  = v0 + v1;
            float s2 = v0 * v0 + v1 * v1;
            #pragma unroll
            for (int off = 1; off < 16; off <<= 1) {
                s  += __shfl_xor(s,  off, 16);
                s2 += __shfl_xor(s2, off, 16);
            }
            if (lm == 0) {
                const int em = et * 16 + q * 4 + r;
                rS [em][w] = s;
                rS2[em][w] = s2;
            }
        }
    }
    __syncthreads();

    #pragma unroll
    for (int et = 0; et < 4; ++et) {
        #pragma unroll
        for (int r = 0; r < 4; ++r) {
            const int em = et * 16 + q * 4 + r;
            const int gn = n0 + em;
            if (gn >= N) continue;
            float4 p  = *(const float4*)&rS [em][0];
            float4 p2 = *(const float4*)&rS2[em][0];
            const float S    = (p.x  + p.y)  + (p.z  + p.w);
            const float S2   = (p2.x + p2.y) + (p2.z + p2.w);
            const float mu   = S * (1.f / 128.f);
            const float var  = S2 * (1.f / 128.f) - mu * mu;
            const float rstd = rsqrtf(var + LN_EPS);
            #pragma unroll
            for (int c2 = 0; c2 < 2; ++c2) {
                const int col = (2 * w + c2) * 16 + lm;
                float y = (acc[et][c2][r] - mu) * rstd * g2v[c2] + bev[c2];
                y = (y > 0.f) ? y : NEG * y;
                float rr = y + x[(size_t)gn * D_NODE + col];
                rr = (rr > 0.f) ? rr : NEG * rr;
                out[(size_t)gn * D_NODE + col] = rr;
            }
        }
    }
}

// ---------------------------------------------------------------------------
extern "C" void kernel_launch(void* const* d_in, const int* in_sizes, int n_in,
                              void* d_out, int out_size, void* d_ws, size_t ws_size,
                              hipStream_t stream) {
    const float* x          = (const float*)d_in[0];
    const int*   edge_index = (const int*)  d_in[1];
    const float* edge_attr  = (const float*)d_in[2];
    const float* W1         = (const float*)d_in[3];
    const float* b1         = (const float*)d_in[4];
    const float* g1         = (const float*)d_in[5];
    const float* be1        = (const float*)d_in[6];
    const float* W2         = (const float*)d_in[7];
    const float* b2         = (const float*)d_in[8];
    const float* g2         = (const float*)d_in[9];
    const float* be2        = (const float*)d_in[10];

    const int N = in_sizes[0] / D_NODE;     // 50000
    const int E = in_sizes[1] / 2;          // 600000

    float* sums     = (float*)d_ws;                        // N*128 f32
    int*   hist     = (int*)(sums + (size_t)N * D_NODE);   // N
    int*   base     = hist + N;                            // N
    int*   blockTot = base + N;                            // 64
    int*   perm     = blockTot + 64;                       // E
    int*   srcrow   = perm + E;                            // E
    int*   dstcol   = srcrow + E;                          // E   (~33 MB total)

    // zero sums + hist in one shot
    hipMemsetAsync(d_ws, 0, ((size_t)N * D_NODE + (size_t)N) * sizeof(float), stream);

    k_hist<<<dim3(256), dim3(256), 0, stream>>>(edge_index, hist, E);
    const int NB = (N + 1023) / 1024;                      // 49 (<=64)
    k_scanA<<<dim3(NB), dim3(1024), 0, stream>>>(hist, base, blockTot, N);
    k_scanB<<<dim3(1),  dim3(64),   0, stream>>>(blockTot, NB);
    k_scanC<<<dim3(NB), dim3(1024), 0, stream>>>(base, blockTot, N);
    k_bucket<<<dim3(256), dim3(256), 0, stream>>>(edge_index, base, perm, srcrow, dstcol, E);

    const int ntiles = (E + 63) / 64;
    const int grid   = ntiles < 1280 ? ntiles : 1280;      // 5 blocks/CU (LDS-limited)
    edge_mfma_seg<<<dim3(grid), dim3(256), 0, stream>>>(
        x, edge_attr, perm, srcrow, dstcol, W1, b1, g1, be1, sums, E, ntiles);

    node_mfma<<<dim3((N + 63) / 64), dim3(256), 0, stream>>>(
        sums, hist, x, W2, b2, g2, be2, (float*)d_out, N);
}